// Round 17
// baseline (200.135 us; speedup 1.0000x reference)
//
#include <hip/hip_runtime.h>
#include <stdint.h>

#define DEVINL __device__ __forceinline__

typedef __attribute__((ext_vector_type(8))) __bf16 bf16x8;
typedef __attribute__((ext_vector_type(4))) float f32x4;
typedef __attribute__((ext_vector_type(8))) unsigned short u16x8;
typedef __attribute__((ext_vector_type(2))) unsigned int u32x2;

// Problem constants
constexpr int Bc = 4, Sc = 2048, DINc = 1024, Hc = 16;
constexpr float QSCALE = 0.18033688011112042f;  // 1/sqrt(64) * log2(e), folded into Q

DEVINL unsigned short f2bf(float x) {
  unsigned u = __builtin_bit_cast(unsigned, x);
  u += 0x7fffu + ((u >> 16) & 1u);   // RNE
  return (unsigned short)(u >> 16);
}

// pack two positive floats' bf16 truncations into one u32 (1 v_perm each):
// bytes = [p0.b2, p0.b3, p1.b2, p1.b3]; sel 0-3 = second operand, 4-7 = first.
DEVINL unsigned pack_bf16_trunc(float p0, float p1) {
  return __builtin_amdgcn_perm(__builtin_bit_cast(unsigned, p1),
                               __builtin_bit_cast(unsigned, p0), 0x07060302u);
}

DEVINL void gload_lds16(const void* g, void* l) {
  __builtin_amdgcn_global_load_lds(
      (const __attribute__((address_space(1))) void*)g,
      (__attribute__((address_space(3))) void*)l, 16, 0, 0);
}

// Stage a [ROWS][64] bf16 tile (global row stride `ld` elements) into LDS.
// LDS dest linear (global_load_lds requirement); SOURCE column XOR-swizzled
// so ds_read_b128 at byte = row*128 + ((2k) ^ ((row&7)<<4)) is conflict-free
// (T2, m173 both-sides pattern). 256 threads.
template <int ROWS>
DEVINL void stage_tile(const unsigned short* g, int ld, void* lds, int tid) {
#pragma unroll
  for (int p = 0; p < ROWS / 32; ++p) {
    int L = (p * 256 + tid) * 16;  // linear LDS byte offset
    int row = L >> 7;              // 128 B per row
    int cb = L & 127;
    int scb = cb ^ ((row & 7) << 4);
    gload_lds16((const char*)(g + (size_t)row * ld) + scb, (char*)lds + L);
  }
}

// Read one MFMA fragment (8 contiguous-K bf16) from a swizzled [*][64] tile.
DEVINL bf16x8 read_frag(const void* lds, int row, int kelem) {
  int addr = row * 128 + (((kelem * 2) ^ ((row & 7) << 4)));
  return *(const bf16x8*)((const char*)lds + addr);
}

// ------------------------------------------------------- fused input prep
// blocks 0..4095: x fp32 -> bf16 (8 elem/thread). blocks 4096..5119: 4-way
// transpose-convert of Wq/Wk/Wv/Wo (z = (bid-4096)>>8). R15-proven.
__global__ __launch_bounds__(256) void prep_inputs(
    const float* __restrict__ x, const float* __restrict__ Wq,
    const float* __restrict__ Wk, const float* __restrict__ Wv,
    const float* __restrict__ Wo, unsigned short* __restrict__ xb,
    unsigned short* __restrict__ wqkvt, unsigned short* __restrict__ wot) {
  __shared__ float t[64][65];
  int bid = blockIdx.x;
  if (bid < 4096) {
    int i = (bid * 256 + threadIdx.x) * 8;
    f32x4 a = *(const f32x4*)(x + i);
    f32x4 b = *(const f32x4*)(x + i + 4);
    u16x8 r;
    r[0] = f2bf(a[0]); r[1] = f2bf(a[1]); r[2] = f2bf(a[2]); r[3] = f2bf(a[3]);
    r[4] = f2bf(b[0]); r[5] = f2bf(b[1]); r[6] = f2bf(b[2]); r[7] = f2bf(b[3]);
    *(u16x8*)(xb + i) = r;
    return;
  }
  int bid2 = bid - 4096;
  int z = bid2 >> 8, rem = bid2 & 255;
  const float* src;
  unsigned short* dst;
  if (z == 0)      { src = Wq; dst = wqkvt; }
  else if (z == 1) { src = Wk; dst = wqkvt + (size_t)1024 * 1024; }
  else if (z == 2) { src = Wv; dst = wqkvt + (size_t)2048 * 1024; }
  else             { src = Wo; dst = wot; }
  int n0 = (rem & 15) * 64, k0 = (rem >> 4) * 64;
  int tx = threadIdx.x & 63, ty = threadIdx.x >> 6;
#pragma unroll
  for (int r = 0; r < 64; r += 4)
    t[r + ty][tx] = src[(size_t)(k0 + r + ty) * 1024 + n0 + tx];
  __syncthreads();
#pragma unroll
  for (int r = 0; r < 64; r += 4)
    dst[(size_t)(n0 + r + ty) * 1024 + k0 + tx] = f2bf(t[tx][r + ty]);
}

// ---------------------------------------------------------------- GEMM1: QKV
// C[8192][3072] = xb[8192][1024] @ Wqkv (Bt is [3072][1024] = W^T)
// K-loop: m97-verified SINGLE-BUFFER 2-barrier structure at 3 blocks/CU
// (R16-proven: ~860 TF, at the documented 2-barrier ceiling). LDS =
// max(32KB staging, 33KB epilogue scratch). R11-proven epilogue via LDS
// roundtrip -> coalesced 16B stores.
__global__ __launch_bounds__(256, 3) void gemm_qkv(
    const unsigned short* __restrict__ A, const unsigned short* __restrict__ Bt,
    unsigned short* __restrict__ qws, unsigned short* __restrict__ kws,
    unsigned short* __restrict__ vtws) {
  __shared__ __align__(16) char lsmem[33792];              // 33 KB (union)
  unsigned short* lA0 = (unsigned short*)lsmem;            // [128*64] 16 KB
  unsigned short* lB0 = (unsigned short*)(lsmem + 16384);  // [128*64] 16 KB
  int tid = threadIdx.x, lane = tid & 63, wave = tid >> 6;
  int wr = wave >> 1, wc = wave & 1;
  int bm = blockIdx.x, bn = blockIdx.y;
  const unsigned short* Ab = A + (size_t)bm * 128 * 1024;
  const unsigned short* Bb = Bt + (size_t)bn * 128 * 1024;
  int r15 = lane & 15, g4 = lane >> 4, khi = g4 * 8;

  f32x4 acc[4][4];
#pragma unroll
  for (int i = 0; i < 4; ++i)
#pragma unroll
    for (int j = 0; j < 4; ++j) acc[i][j] = (f32x4){0.f, 0.f, 0.f, 0.f};

#pragma unroll 1
  for (int t = 0; t < 16; ++t) {
    stage_tile<128>(Ab + t * 64, 1024, lA0, tid);
    stage_tile<128>(Bb + t * 64, 1024, lB0, tid);
    __syncthreads();  // drains staging (vmcnt(0) before barrier)
#pragma unroll
    for (int ks = 0; ks < 2; ++ks) {
      bf16x8 af[4], bfr[4];
#pragma unroll
      for (int i = 0; i < 4; ++i)
        af[i] = read_frag(lA0, wr * 64 + i * 16 + r15, ks * 32 + khi);
#pragma unroll
      for (int j = 0; j < 4; ++j)
        bfr[j] = read_frag(lB0, wc * 64 + j * 16 + r15, ks * 32 + khi);
      __builtin_amdgcn_s_setprio(1);
#pragma unroll
      for (int i = 0; i < 4; ++i)
#pragma unroll
        for (int j = 0; j < 4; ++j)
          acc[i][j] = __builtin_amdgcn_mfma_f32_16x16x32_bf16(af[i], bfr[j], acc[i][j], 0, 0, 0);
      __builtin_amdgcn_s_setprio(0);
    }
    __syncthreads();  // all reads done before next stage overwrites
  }

  // -------- epilogue via LDS roundtrip (coalesced 16B stores) --------
  int sel = bn >> 3;                 // 0=Q 1=K 2=V (block-uniform)
  float* sc = (float*)lsmem;         // [64][132] f32 = 33792 B, overlays staging
  constexpr int PADW = 132;          // rows 16B-aligned, col reads 2-way/free
  int bq = (bm * 128) >> 11;         // batch index (tile never crosses a b boundary)
#pragma unroll 1
  for (int pass = 0; pass < 2; ++pass) {
    __syncthreads();  // staging reads (or pass-0 reads) done; safe to overwrite
    if (wr == pass) { // waves owning rows [pass*64, pass*64+64)
#pragma unroll
      for (int i = 0; i < 4; ++i)
#pragma unroll
        for (int j = 0; j < 4; ++j)
#pragma unroll
          for (int r = 0; r < 4; ++r) {
            float v = acc[i][j][r];
            if (sel == 0) v *= QSCALE;
            sc[(i * 16 + g4 * 4 + r) * PADW + wc * 64 + j * 16 + r15] = v;
          }
    }
    __syncthreads();
    if (sel < 2) {
      // Q/K: row-major reads -> [bh][s][d] stores, 4 x 16B per thread
      int row = tid >> 2, c0 = (tid & 3) * 32;
      int m = bm * 128 + pass * 64 + row;
      int s = m & 2047;
      int colg = (bn & 7) * 128 + c0;
      int h = colg >> 6, d0 = colg & 63;
      unsigned short* dst =
          (sel == 0 ? qws : kws) + ((size_t)(bq * 16 + h) * 2048 + s) * 64 + d0;
#pragma unroll
      for (int q = 0; q < 4; ++q) {
        f32x4 a = *(const f32x4*)&sc[row * PADW + c0 + q * 8];
        f32x4 b2 = *(const f32x4*)&sc[row * PADW + c0 + q * 8 + 4];
        u16x8 o;
        o[0] = f2bf(a[0]);  o[1] = f2bf(a[1]);  o[2] = f2bf(a[2]);  o[3] = f2bf(a[3]);
        o[4] = f2bf(b2[0]); o[5] = f2bf(b2[1]); o[6] = f2bf(b2[2]); o[7] = f2bf(b2[3]);
        *(u16x8*)(dst + q * 8) = o;
      }
    } else {
      // V: column reads (stride PADW, 2-way=free) -> [bh][d][s] stores
      int col = tid >> 1, s0loc = (tid & 1) * 32;
      int colg = (bn & 7) * 128 + col;
      int h = colg >> 6, d = colg & 63;
      int sbase = (bm * 128 + pass * 64 + s0loc) & 2047;
      unsigned short* dst =
          vtws + ((size_t)(bq * 16 + h) * 64 + d) * 2048 + sbase;
#pragma unroll
      for (int q = 0; q < 4; ++q) {
        u16x8 o;
#pragma unroll
        for (int e = 0; e < 8; ++e)
          o[e] = f2bf(sc[(s0loc + q * 8 + e) * PADW + col]);
        *(u16x8*)(dst + q * 8) = o;
      }
    }
  }
}

// ---------------------------------------------------------------- attention
// grid (8, 128) = 1024 blocks, 256 threads = 4 waves x 32 q-rows. R10/R16-
// proven structure (65.3us measured): one q-tile per block, heavy-first
// t = 15-(by>>3), XCD-local bh = bx*8 + (by&7) (L2-resident K/V, FETCH 27MB).
// K and V^T double-buffered in LDS, one barrier per k-iteration.
// R17 CHANGE (one mechanism): lP shrunk 16KB -> 8KB by processing P per mf
// HALF (16 rows): {write P half, read pf, 8 PV MFMA} x2. DS ops are in-order
// per wave, so the half-buffer WAR reuse needs NO new barrier. LDS 48->40KB
// => 4 blocks/CU (launch_bounds(256,4), VGPR 72 << 128 cap, no spill).
// V-in-registers PERMANENTLY BANNED (R6+R12 spills). cvt_pk asm BANNED (R4).
__global__ __launch_bounds__(256, 4) void attn(
    const unsigned short* __restrict__ qws, const unsigned short* __restrict__ kws,
    const unsigned short* __restrict__ vtws, unsigned short* __restrict__ ctx) {
  __shared__ __align__(16) unsigned short lK[2][64 * 64];   // 16 KB
  __shared__ __align__(16) unsigned short lV[2][64 * 64];   // 16 KB
  __shared__ __align__(16) unsigned short lP[4][16 * 64];   //  8 KB (per-mf half)
  int tid = threadIdx.x, lane = tid & 63, wave = tid >> 6;
  int bh = blockIdx.x * 8 + (blockIdx.y & 7);
  int t = 15 - (int)(blockIdx.y >> 3);  // heavy-first
  int r15 = lane & 15, g4 = lane >> 4;
  const unsigned short* Kb = kws + (size_t)bh * 2048 * 64;
  const unsigned short* Vb = vtws + (size_t)bh * 64 * 2048;
  int b = bh >> 4, h = bh & 15;
  char* Pw = (char*)&lP[wave][0];

  int q0 = t * 128;
  int myrow0 = q0 + wave * 32;
  const unsigned short* Qb = qws + ((size_t)bh * 2048 + myrow0) * 64;

  // Q fragments in registers (pre-scaled). Serves as MFMA B-operand
  // (col = lane&15 = q-row, k = d contiguous).
  bf16x8 qf[2][2];
#pragma unroll
  for (int mf = 0; mf < 2; ++mf)
#pragma unroll
    for (int ks = 0; ks < 2; ++ks)
      qf[mf][ks] = *(const bf16x8*)(Qb + (size_t)(mf * 16 + r15) * 64 + ks * 32 + g4 * 8);

  // per-lane softmax state for q = myrow0 + mf*16 + (lane&15)
  float m_run[2] = {-1e30f, -1e30f}, l_run[2] = {0.f, 0.f};
  f32x4 o_acc[2][4];
#pragma unroll
  for (int mf = 0; mf < 2; ++mf)
#pragma unroll
    for (int df = 0; df < 4; ++df) o_acc[mf][df] = (f32x4){0.f, 0.f, 0.f, 0.f};

  int nkt = 2 * t + 2;
  int cur = 0;
  stage_tile<64>(Kb, 64, lK[0], tid);
  stage_tile<64>(Vb, 2048, lV[0], tid);

#pragma unroll 1
  for (int kt = 0; kt < nkt; ++kt) {
    __syncthreads();  // buf[cur] landed; reads of buf[cur^1] done
    if (kt + 1 < nkt) {
      stage_tile<64>(Kb + (size_t)(kt + 1) * 64 * 64, 64, lK[cur ^ 1], tid);
      stage_tile<64>(Vb + (size_t)(kt + 1) * 64, 2048, lV[cur ^ 1], tid);
    }

    // S^T = K Q^T : col = q (lane&15), row = key (g4*4+r)
    f32x4 sacc[2][4];
#pragma unroll
    for (int mf = 0; mf < 2; ++mf)
#pragma unroll
      for (int nf = 0; nf < 4; ++nf) sacc[mf][nf] = (f32x4){0.f, 0.f, 0.f, 0.f};
#pragma unroll
    for (int ks = 0; ks < 2; ++ks) {
      bf16x8 kf[4];
#pragma unroll
      for (int nf = 0; nf < 4; ++nf)
        kf[nf] = read_frag(lK[cur], nf * 16 + r15, ks * 32 + g4 * 8);
      __builtin_amdgcn_s_setprio(1);
#pragma unroll
      for (int mf = 0; mf < 2; ++mf)
#pragma unroll
        for (int nf = 0; nf < 4; ++nf)
          sacc[mf][nf] = __builtin_amdgcn_mfma_f32_16x16x32_bf16(kf[nf], qf[mf][ks], sacc[mf][nf], 0, 0, 0);
      __builtin_amdgcn_s_setprio(0);
    }

    // causal mask: key > q  (only tiles crossing this wave's rows)
    if (kt * 64 + 63 > myrow0) {
#pragma unroll
      for (int mf = 0; mf < 2; ++mf) {
        int q = myrow0 + mf * 16 + r15;
#pragma unroll
        for (int nf = 0; nf < 4; ++nf) {
          int kbase = kt * 64 + nf * 16 + g4 * 4;
#pragma unroll
          for (int r = 0; r < 4; ++r)
            if (kbase + r > q) sacc[mf][nf][r] = -3e38f;
        }
      }
    }

    // per-q tile max: 15 in-lane fmax + 2 shuffles (keys spread over g4)
    float tm[2];
#pragma unroll
    for (int mf = 0; mf < 2; ++mf) {
      float a0 = fmaxf(fmaxf(sacc[mf][0][0], sacc[mf][0][1]), fmaxf(sacc[mf][0][2], sacc[mf][0][3]));
      float a1 = fmaxf(fmaxf(sacc[mf][1][0], sacc[mf][1][1]), fmaxf(sacc[mf][1][2], sacc[mf][1][3]));
      float a2 = fmaxf(fmaxf(sacc[mf][2][0], sacc[mf][2][1]), fmaxf(sacc[mf][2][2], sacc[mf][2][3]));
      float a3 = fmaxf(fmaxf(sacc[mf][3][0], sacc[mf][3][1]), fmaxf(sacc[mf][3][2], sacc[mf][3][3]));
      float m = fmaxf(fmaxf(a0, a1), fmaxf(a2, a3));
      m = fmaxf(m, __shfl_xor(m, 16));
      m = fmaxf(m, __shfl_xor(m, 32));
      tm[mf] = m;
    }

    // defer-max (T13): rescale only if some row grew by > 11.5 (base-2)
    bool ok = (tm[0] <= m_run[0] + 11.5f) & (tm[1] <= m_run[1] + 11.5f);
    if (!__all(ok)) {
#pragma unroll
      for (int mf = 0; mf < 2; ++mf) {
        float mn = fmaxf(m_run[mf], tm[mf]);
        float a = __builtin_amdgcn_exp2f(m_run[mf] - mn);
        m_run[mf] = mn;
        l_run[mf] *= a;
        // o_acc rows are q = g4*4 + r -> fetch alpha from lane (q | upper)
        float av[4];
#pragma unroll
        for (int r = 0; r < 4; ++r)
          av[r] = __shfl(a, (g4 * 4 + r) | (lane & 48));
#pragma unroll
        for (int df = 0; df < 4; ++df)
#pragma unroll
          for (int r = 0; r < 4; ++r) o_acc[mf][df][r] *= av[r];
      }
    }

    // V^T fragments for this tile (shared by both mf halves)
    bf16x8 vf[4][2];
#pragma unroll
    for (int ks = 0; ks < 2; ++ks)
#pragma unroll
      for (int df = 0; df < 4; ++df)
        vf[df][ks] = read_frag(lV[cur], df * 16 + r15, ks * 32 + g4 * 8);

    // Per mf HALF: P = exp2(S^T - m) -> 16-row LDS half-buffer -> PV MFMA.
    // DS ops are in-order per wave: the mf=1 writes cannot pass the mf=0
    // pf reads, so reusing the half-buffer needs no barrier.
#pragma unroll
    for (int mf = 0; mf < 2; ++mf) {
      char* Prow = Pw + r15 * 128;
      int sw = (r15 & 7) << 4;
      float rs = 0.f;
#pragma unroll
      for (int nf = 0; nf < 4; ++nf) {
        float p0 = __builtin_amdgcn_exp2f(sacc[mf][nf][0] - m_run[mf]);
        float p1 = __builtin_amdgcn_exp2f(sacc[mf][nf][1] - m_run[mf]);
        float p2 = __builtin_amdgcn_exp2f(sacc[mf][nf][2] - m_run[mf]);
        float p3 = __builtin_amdgcn_exp2f(sacc[mf][nf][3] - m_run[mf]);
        rs += (p0 + p1) + (p2 + p3);
        *(u32x2*)(Prow + (((nf * 16 + g4 * 4) * 2) ^ sw)) =
            (u32x2){pack_bf16_trunc(p0, p1), pack_bf16_trunc(p2, p3)};
      }
      rs += __shfl_xor(rs, 16);
      rs += __shfl_xor(rs, 32);
      l_run[mf] += rs;

#pragma unroll
      for (int ks = 0; ks < 2; ++ks) {
        bf16x8 pf = read_frag(Pw, r15, ks * 32 + g4 * 8);
        __builtin_amdgcn_s_setprio(1);
#pragma unroll
        for (int df = 0; df < 4; ++df)
          o_acc[mf][df] = __builtin_amdgcn_mfma_f32_16x16x32_bf16(pf, vf[df][ks], o_acc[mf][df], 0, 0, 0);
        __builtin_amdgcn_s_setprio(0);
      }
    }
    cur ^= 1;
  }

  // epilogue: l_run lives at lane&15 = q; o_acc rows are q = g4*4+r
#pragma unroll
  for (int mf = 0; mf < 2; ++mf) {
    float rl = 1.f / l_run[mf];
    float rv[4];
#pragma unroll
    for (int r = 0; r < 4; ++r)
      rv[r] = __shfl(rl, (g4 * 4 + r) | (lane & 48));
#pragma unroll
    for (int r = 0; r < 4; ++r) {
      int row = myrow0 + mf * 16 + g4 * 4 + r;
#pragma unroll
      for (int df = 0; df < 4; ++df)
        ctx[((size_t)(b * 2048 + row)) * 1024 + h * 64 + df * 16 + r15] =
            f2bf(o_acc[mf][df][r] * rv[r]);
    }
  }
}

// ---------------------------------------------------------------- GEMM2: out
// out[8192][1024] fp32 = ctx[8192][1024] @ Wo (Bt = Wo^T [1024][1024]) + bo
// m97-structure single-buffer 2-barrier K-loop at 3 blocks/CU (R16-proven).
// Direct epilogue (R13: stores already coalesced; LDS roundtrip hurt).
__global__ __launch_bounds__(256, 3) void gemm_out(
    const unsigned short* __restrict__ A, const unsigned short* __restrict__ Bt,
    const float* __restrict__ bo, float* __restrict__ out) {
  __shared__ __align__(16) unsigned short lA[128 * 64];
  __shared__ __align__(16) unsigned short lB[128 * 64];
  int tid = threadIdx.x, lane = tid & 63, wave = tid >> 6;
  int wr = wave >> 1, wc = wave & 1;
  int bm = blockIdx.x, bn = blockIdx.y;
  const unsigned short* Ab = A + (size_t)bm * 128 * 1024;
  const unsigned short* Bb = Bt + (size_t)bn * 128 * 1024;
  int r15 = lane & 15, khi = (lane >> 4) * 8;

  f32x4 acc[4][4];
#pragma unroll
  for (int i = 0; i < 4; ++i)
#pragma unroll
    for (int j = 0; j < 4; ++j) acc[i][j] = (f32x4){0.f, 0.f, 0.f, 0.f};

#pragma unroll 1
  for (int t = 0; t < 16; ++t) {
    stage_tile<128>(Ab + t * 64, 1024, lA, tid);
    stage_tile<128>(Bb + t * 64, 1024, lB, tid);
    __syncthreads();
#pragma unroll
    for (int ks = 0; ks < 2; ++ks) {
      bf16x8 af[4], bfr[4];
#pragma unroll
      for (int i = 0; i < 4; ++i)
        af[i] = read_frag(lA, wr * 64 + i * 16 + r15, ks * 32 + khi);
#pragma unroll
      for (int j = 0; j < 4; ++j)
        bfr[j] = read_frag(lB, wc * 64 + j * 16 + r15, ks * 32 + khi);
      __builtin_amdgcn_s_setprio(1);
#pragma unroll
      for (int i = 0; i < 4; ++i)
#pragma unroll
        for (int j = 0; j < 4; ++j)
          acc[i][j] = __builtin_amdgcn_mfma_f32_16x16x32_bf16(af[i], bfr[j], acc[i][j], 0, 0, 0);
      __builtin_amdgcn_s_setprio(0);
    }
    __syncthreads();
  }

  int nbase = bn * 128 + wc * 64;
  int mbase = bm * 128 + wr * 64;
#pragma unroll
  for (int j = 0; j < 4; ++j) {
    int n = nbase + j * 16 + r15;
    float bias = bo[n];
#pragma unroll
    for (int i = 0; i < 4; ++i)
#pragma unroll
      for (int r = 0; r < 4; ++r) {
        int m = mbase + i * 16 + (lane >> 4) * 4 + r;
        out[(size_t)m * 1024 + n] = acc[i][j][r] + bias;
      }
  }
}

// ---------------------------------------------------------------- launch
extern "C" void kernel_launch(void* const* d_in, const int* in_sizes, int n_in,
                              void* d_out, int out_size, void* d_ws, size_t ws_size,
                              hipStream_t stream) {
  const float* x = (const float*)d_in[0];
  const float* Wq = (const float*)d_in[1];
  const float* Wk = (const float*)d_in[2];
  const float* Wv = (const float*)d_in[3];
  const float* Wo = (const float*)d_in[4];
  const float* bo = (const float*)d_in[5];
  float* out = (float*)d_out;

  char* ws = (char*)d_ws;
  unsigned short* xb    = (unsigned short*)(ws);                    // 16 MiB
  unsigned short* wqkvt = (unsigned short*)(ws + (16u << 20));      //  6 MiB
  unsigned short* wot   = (unsigned short*)(ws + (22u << 20));      //  2 MiB
  unsigned short* qws   = (unsigned short*)(ws + (24u << 20));      // 16 MiB
  unsigned short* kws   = (unsigned short*)(ws + (40u << 20));      // 16 MiB
  unsigned short* vtws  = (unsigned short*)(ws + (56u << 20));      // 16 MiB
  unsigned short* ctxws = (unsigned short*)(ws + (72u << 20));      // 16 MiB  (total 88 MiB)

  prep_inputs<<<dim3(5120), dim3(256), 0, stream>>>(x, Wq, Wk, Wv, Wo, xb, wqkvt, wot);

  gemm_qkv<<<dim3(64, 24), dim3(256), 0, stream>>>(xb, wqkvt, qws, kws, vtws);
  attn<<<dim3(8, 128), dim3(256), 0, stream>>>(qws, kws, vtws, ctxws);
  gemm_out<<<dim3(64, 8), dim3(256), 0, stream>>>(ctxws, wot, bo, out);
}

// Round 18
// 164.878 us; speedup vs baseline: 1.2138x; 1.2138x over previous
//
#include <hip/hip_runtime.h>
#include <stdint.h>

#define DEVINL __device__ __forceinline__

typedef __attribute__((ext_vector_type(8))) __bf16 bf16x8;
typedef __attribute__((ext_vector_type(4))) float f32x4;
typedef __attribute__((ext_vector_type(8))) unsigned short u16x8;
typedef __attribute__((ext_vector_type(2))) unsigned int u32x2;

// Problem constants
constexpr int Bc = 4, Sc = 2048, DINc = 1024, Hc = 16;
constexpr float QSCALE = 0.18033688011112042f;  // 1/sqrt(64) * log2(e), folded into Q

DEVINL unsigned short f2bf(float x) {
  unsigned u = __builtin_bit_cast(unsigned, x);
  u += 0x7fffu + ((u >> 16) & 1u);   // RNE
  return (unsigned short)(u >> 16);
}

// pack two positive floats' bf16 truncations into one u32 (1 v_perm each):
// bytes = [p0.b2, p0.b3, p1.b2, p1.b3]; sel 0-3 = second operand, 4-7 = first.
DEVINL unsigned pack_bf16_trunc(float p0, float p1) {
  return __builtin_amdgcn_perm(__builtin_bit_cast(unsigned, p1),
                               __builtin_bit_cast(unsigned, p0), 0x07060302u);
}

DEVINL void gload_lds16(const void* g, void* l) {
  __builtin_amdgcn_global_load_lds(
      (const __attribute__((address_space(1))) void*)g,
      (__attribute__((address_space(3))) void*)l, 16, 0, 0);
}

// Stage a [ROWS][64] bf16 tile (global row stride `ld` elements) into LDS.
// LDS dest linear (global_load_lds requirement); SOURCE column XOR-swizzled
// so ds_read_b128 at byte = row*128 + ((2k) ^ ((row&7)<<4)) is conflict-free
// (T2, m173 both-sides pattern). 256 threads.
template <int ROWS>
DEVINL void stage_tile(const unsigned short* g, int ld, void* lds, int tid) {
#pragma unroll
  for (int p = 0; p < ROWS / 32; ++p) {
    int L = (p * 256 + tid) * 16;  // linear LDS byte offset
    int row = L >> 7;              // 128 B per row
    int cb = L & 127;
    int scb = cb ^ ((row & 7) << 4);
    gload_lds16((const char*)(g + (size_t)row * ld) + scb, (char*)lds + L);
  }
}

// Read one MFMA fragment (8 contiguous-K bf16) from a swizzled [*][64] tile.
DEVINL bf16x8 read_frag(const void* lds, int row, int kelem) {
  int addr = row * 128 + (((kelem * 2) ^ ((row & 7) << 4)));
  return *(const bf16x8*)((const char*)lds + addr);
}

// ------------------------------------------------------- fused input prep
// blocks 0..4095: x fp32 -> bf16 (8 elem/thread). blocks 4096..5119: 4-way
// transpose-convert of Wq/Wk/Wv/Wo (z = (bid-4096)>>8). R15-proven.
__global__ __launch_bounds__(256) void prep_inputs(
    const float* __restrict__ x, const float* __restrict__ Wq,
    const float* __restrict__ Wk, const float* __restrict__ Wv,
    const float* __restrict__ Wo, unsigned short* __restrict__ xb,
    unsigned short* __restrict__ wqkvt, unsigned short* __restrict__ wot) {
  __shared__ float t[64][65];
  int bid = blockIdx.x;
  if (bid < 4096) {
    int i = (bid * 256 + threadIdx.x) * 8;
    f32x4 a = *(const f32x4*)(x + i);
    f32x4 b = *(const f32x4*)(x + i + 4);
    u16x8 r;
    r[0] = f2bf(a[0]); r[1] = f2bf(a[1]); r[2] = f2bf(a[2]); r[3] = f2bf(a[3]);
    r[4] = f2bf(b[0]); r[5] = f2bf(b[1]); r[6] = f2bf(b[2]); r[7] = f2bf(b[3]);
    *(u16x8*)(xb + i) = r;
    return;
  }
  int bid2 = bid - 4096;
  int z = bid2 >> 8, rem = bid2 & 255;
  const float* src;
  unsigned short* dst;
  if (z == 0)      { src = Wq; dst = wqkvt; }
  else if (z == 1) { src = Wk; dst = wqkvt + (size_t)1024 * 1024; }
  else if (z == 2) { src = Wv; dst = wqkvt + (size_t)2048 * 1024; }
  else             { src = Wo; dst = wot; }
  int n0 = (rem & 15) * 64, k0 = (rem >> 4) * 64;
  int tx = threadIdx.x & 63, ty = threadIdx.x >> 6;
#pragma unroll
  for (int r = 0; r < 64; r += 4)
    t[r + ty][tx] = src[(size_t)(k0 + r + ty) * 1024 + n0 + tx];
  __syncthreads();
#pragma unroll
  for (int r = 0; r < 64; r += 4)
    dst[(size_t)(n0 + r + ty) * 1024 + k0 + tx] = f2bf(t[tx][r + ty]);
}

// ---------------------------------------------------------------- GEMM1: QKV
// C[8192][3072] = xb[8192][1024] @ Wqkv (Bt is [3072][1024] = W^T)
// K-loop: m97-verified SINGLE-BUFFER 2-barrier structure at 3 blocks/CU
// (R16-proven: ~860 TF, at the documented 2-barrier ceiling). LDS =
// max(32KB staging, 33KB epilogue scratch). R11-proven epilogue via LDS
// roundtrip -> coalesced 16B stores.
__global__ __launch_bounds__(256, 3) void gemm_qkv(
    const unsigned short* __restrict__ A, const unsigned short* __restrict__ Bt,
    unsigned short* __restrict__ qws, unsigned short* __restrict__ kws,
    unsigned short* __restrict__ vtws) {
  __shared__ __align__(16) char lsmem[33792];              // 33 KB (union)
  unsigned short* lA0 = (unsigned short*)lsmem;            // [128*64] 16 KB
  unsigned short* lB0 = (unsigned short*)(lsmem + 16384);  // [128*64] 16 KB
  int tid = threadIdx.x, lane = tid & 63, wave = tid >> 6;
  int wr = wave >> 1, wc = wave & 1;
  int bm = blockIdx.x, bn = blockIdx.y;
  const unsigned short* Ab = A + (size_t)bm * 128 * 1024;
  const unsigned short* Bb = Bt + (size_t)bn * 128 * 1024;
  int r15 = lane & 15, g4 = lane >> 4, khi = g4 * 8;

  f32x4 acc[4][4];
#pragma unroll
  for (int i = 0; i < 4; ++i)
#pragma unroll
    for (int j = 0; j < 4; ++j) acc[i][j] = (f32x4){0.f, 0.f, 0.f, 0.f};

#pragma unroll 1
  for (int t = 0; t < 16; ++t) {
    stage_tile<128>(Ab + t * 64, 1024, lA0, tid);
    stage_tile<128>(Bb + t * 64, 1024, lB0, tid);
    __syncthreads();  // drains staging (vmcnt(0) before barrier)
#pragma unroll
    for (int ks = 0; ks < 2; ++ks) {
      bf16x8 af[4], bfr[4];
#pragma unroll
      for (int i = 0; i < 4; ++i)
        af[i] = read_frag(lA0, wr * 64 + i * 16 + r15, ks * 32 + khi);
#pragma unroll
      for (int j = 0; j < 4; ++j)
        bfr[j] = read_frag(lB0, wc * 64 + j * 16 + r15, ks * 32 + khi);
      __builtin_amdgcn_s_setprio(1);
#pragma unroll
      for (int i = 0; i < 4; ++i)
#pragma unroll
        for (int j = 0; j < 4; ++j)
          acc[i][j] = __builtin_amdgcn_mfma_f32_16x16x32_bf16(af[i], bfr[j], acc[i][j], 0, 0, 0);
      __builtin_amdgcn_s_setprio(0);
    }
    __syncthreads();  // all reads done before next stage overwrites
  }

  // -------- epilogue via LDS roundtrip (coalesced 16B stores) --------
  int sel = bn >> 3;                 // 0=Q 1=K 2=V (block-uniform)
  float* sc = (float*)lsmem;         // [64][132] f32 = 33792 B, overlays staging
  constexpr int PADW = 132;          // rows 16B-aligned, col reads 2-way/free
  int bq = (bm * 128) >> 11;         // batch index (tile never crosses a b boundary)
#pragma unroll 1
  for (int pass = 0; pass < 2; ++pass) {
    __syncthreads();  // staging reads (or pass-0 reads) done; safe to overwrite
    if (wr == pass) { // waves owning rows [pass*64, pass*64+64)
#pragma unroll
      for (int i = 0; i < 4; ++i)
#pragma unroll
        for (int j = 0; j < 4; ++j)
#pragma unroll
          for (int r = 0; r < 4; ++r) {
            float v = acc[i][j][r];
            if (sel == 0) v *= QSCALE;
            sc[(i * 16 + g4 * 4 + r) * PADW + wc * 64 + j * 16 + r15] = v;
          }
    }
    __syncthreads();
    if (sel < 2) {
      // Q/K: row-major reads -> [bh][s][d] stores, 4 x 16B per thread
      int row = tid >> 2, c0 = (tid & 3) * 32;
      int m = bm * 128 + pass * 64 + row;
      int s = m & 2047;
      int colg = (bn & 7) * 128 + c0;
      int h = colg >> 6, d0 = colg & 63;
      unsigned short* dst =
          (sel == 0 ? qws : kws) + ((size_t)(bq * 16 + h) * 2048 + s) * 64 + d0;
#pragma unroll
      for (int q = 0; q < 4; ++q) {
        f32x4 a = *(const f32x4*)&sc[row * PADW + c0 + q * 8];
        f32x4 b2 = *(const f32x4*)&sc[row * PADW + c0 + q * 8 + 4];
        u16x8 o;
        o[0] = f2bf(a[0]);  o[1] = f2bf(a[1]);  o[2] = f2bf(a[2]);  o[3] = f2bf(a[3]);
        o[4] = f2bf(b2[0]); o[5] = f2bf(b2[1]); o[6] = f2bf(b2[2]); o[7] = f2bf(b2[3]);
        *(u16x8*)(dst + q * 8) = o;
      }
    } else {
      // V: column reads (stride PADW, 2-way=free) -> [bh][d][s] stores
      int col = tid >> 1, s0loc = (tid & 1) * 32;
      int colg = (bn & 7) * 128 + col;
      int h = colg >> 6, d = colg & 63;
      int sbase = (bm * 128 + pass * 64 + s0loc) & 2047;
      unsigned short* dst =
          vtws + ((size_t)(bq * 16 + h) * 64 + d) * 2048 + sbase;
#pragma unroll
      for (int q = 0; q < 4; ++q) {
        u16x8 o;
#pragma unroll
        for (int e = 0; e < 8; ++e)
          o[e] = f2bf(sc[(s0loc + q * 8 + e) * PADW + col]);
        *(u16x8*)(dst + q * 8) = o;
      }
    }
  }
}

// ---------------------------------------------------------------- attention
// grid (8, 128) = 1024 blocks, 256 threads = 4 waves x 32 q-rows. R16-PROVEN
// (65.3us measured): one q-tile per block, heavy-first t = 15-(by>>3),
// XCD-local bh = bx*8 + (by&7) (L2-resident K/V, FETCH 27MB). K and V^T
// double-buffered in LDS, FULL 32-row P tile per wave (R17 lesson: halving
// lP serialized the P write->read->MFMA chain via in-order DS and cost 57%).
// V-in-registers PERMANENTLY BANNED (R6+R12 spills). cvt_pk asm BANNED (R4).
__global__ __launch_bounds__(256, 3) void attn(
    const unsigned short* __restrict__ qws, const unsigned short* __restrict__ kws,
    const unsigned short* __restrict__ vtws, unsigned short* __restrict__ ctx) {
  __shared__ __align__(16) unsigned short lK[2][64 * 64];
  __shared__ __align__(16) unsigned short lV[2][64 * 64];
  __shared__ __align__(16) unsigned short lP[4][32 * 64];
  int tid = threadIdx.x, lane = tid & 63, wave = tid >> 6;
  int bh = blockIdx.x * 8 + (blockIdx.y & 7);
  int t = 15 - (int)(blockIdx.y >> 3);  // heavy-first
  int r15 = lane & 15, g4 = lane >> 4;
  const unsigned short* Kb = kws + (size_t)bh * 2048 * 64;
  const unsigned short* Vb = vtws + (size_t)bh * 64 * 2048;
  int b = bh >> 4, h = bh & 15;
  char* Pw = (char*)&lP[wave][0];

  int q0 = t * 128;
  int myrow0 = q0 + wave * 32;
  const unsigned short* Qb = qws + ((size_t)bh * 2048 + myrow0) * 64;

  // Q fragments in registers (pre-scaled). Serves as MFMA B-operand
  // (col = lane&15 = q-row, k = d contiguous).
  bf16x8 qf[2][2];
#pragma unroll
  for (int mf = 0; mf < 2; ++mf)
#pragma unroll
    for (int ks = 0; ks < 2; ++ks)
      qf[mf][ks] = *(const bf16x8*)(Qb + (size_t)(mf * 16 + r15) * 64 + ks * 32 + g4 * 8);

  // per-lane softmax state for q = myrow0 + mf*16 + (lane&15)
  float m_run[2] = {-1e30f, -1e30f}, l_run[2] = {0.f, 0.f};
  f32x4 o_acc[2][4];
#pragma unroll
  for (int mf = 0; mf < 2; ++mf)
#pragma unroll
    for (int df = 0; df < 4; ++df) o_acc[mf][df] = (f32x4){0.f, 0.f, 0.f, 0.f};

  int nkt = 2 * t + 2;
  int cur = 0;
  stage_tile<64>(Kb, 64, lK[0], tid);
  stage_tile<64>(Vb, 2048, lV[0], tid);

#pragma unroll 1
  for (int kt = 0; kt < nkt; ++kt) {
    __syncthreads();  // buf[cur] landed; reads of buf[cur^1] done
    if (kt + 1 < nkt) {
      stage_tile<64>(Kb + (size_t)(kt + 1) * 64 * 64, 64, lK[cur ^ 1], tid);
      stage_tile<64>(Vb + (size_t)(kt + 1) * 64, 2048, lV[cur ^ 1], tid);
    }

    // S^T = K Q^T : col = q (lane&15), row = key (g4*4+r)
    f32x4 sacc[2][4];
#pragma unroll
    for (int mf = 0; mf < 2; ++mf)
#pragma unroll
      for (int nf = 0; nf < 4; ++nf) sacc[mf][nf] = (f32x4){0.f, 0.f, 0.f, 0.f};
#pragma unroll
    for (int ks = 0; ks < 2; ++ks) {
      bf16x8 kf[4];
#pragma unroll
      for (int nf = 0; nf < 4; ++nf)
        kf[nf] = read_frag(lK[cur], nf * 16 + r15, ks * 32 + g4 * 8);
      __builtin_amdgcn_s_setprio(1);
#pragma unroll
      for (int mf = 0; mf < 2; ++mf)
#pragma unroll
        for (int nf = 0; nf < 4; ++nf)
          sacc[mf][nf] = __builtin_amdgcn_mfma_f32_16x16x32_bf16(kf[nf], qf[mf][ks], sacc[mf][nf], 0, 0, 0);
      __builtin_amdgcn_s_setprio(0);
    }

    // causal mask: key > q  (only tiles crossing this wave's rows)
    if (kt * 64 + 63 > myrow0) {
#pragma unroll
      for (int mf = 0; mf < 2; ++mf) {
        int q = myrow0 + mf * 16 + r15;
#pragma unroll
        for (int nf = 0; nf < 4; ++nf) {
          int kbase = kt * 64 + nf * 16 + g4 * 4;
#pragma unroll
          for (int r = 0; r < 4; ++r)
            if (kbase + r > q) sacc[mf][nf][r] = -3e38f;
        }
      }
    }

    // per-q tile max: 15 in-lane fmax + 2 shuffles (keys spread over g4)
    float tm[2];
#pragma unroll
    for (int mf = 0; mf < 2; ++mf) {
      float a0 = fmaxf(fmaxf(sacc[mf][0][0], sacc[mf][0][1]), fmaxf(sacc[mf][0][2], sacc[mf][0][3]));
      float a1 = fmaxf(fmaxf(sacc[mf][1][0], sacc[mf][1][1]), fmaxf(sacc[mf][1][2], sacc[mf][1][3]));
      float a2 = fmaxf(fmaxf(sacc[mf][2][0], sacc[mf][2][1]), fmaxf(sacc[mf][2][2], sacc[mf][2][3]));
      float a3 = fmaxf(fmaxf(sacc[mf][3][0], sacc[mf][3][1]), fmaxf(sacc[mf][3][2], sacc[mf][3][3]));
      float m = fmaxf(fmaxf(a0, a1), fmaxf(a2, a3));
      m = fmaxf(m, __shfl_xor(m, 16));
      m = fmaxf(m, __shfl_xor(m, 32));
      tm[mf] = m;
    }

    // defer-max (T13): rescale only if some row grew by > 11.5 (base-2)
    bool ok = (tm[0] <= m_run[0] + 11.5f) & (tm[1] <= m_run[1] + 11.5f);
    if (!__all(ok)) {
#pragma unroll
      for (int mf = 0; mf < 2; ++mf) {
        float mn = fmaxf(m_run[mf], tm[mf]);
        float a = __builtin_amdgcn_exp2f(m_run[mf] - mn);
        m_run[mf] = mn;
        l_run[mf] *= a;
        // o_acc rows are q = g4*4 + r -> fetch alpha from lane (q | upper)
        float av[4];
#pragma unroll
        for (int r = 0; r < 4; ++r)
          av[r] = __shfl(a, (g4 * 4 + r) | (lane & 48));
#pragma unroll
        for (int df = 0; df < 4; ++df)
#pragma unroll
          for (int r = 0; r < 4; ++r) o_acc[mf][df][r] *= av[r];
      }
    }

    // P = exp2(S^T - m): 4 consecutive keys per lane -> one b64 write each;
    // bf16 by truncation + v_perm pack (P in [0,1], bias < 2^-8 rel)
    float rs[2] = {0.f, 0.f};
#pragma unroll
    for (int mf = 0; mf < 2; ++mf) {
      int prow = mf * 16 + r15;
      char* Prow = Pw + prow * 128;
      int sw = (prow & 7) << 4;
#pragma unroll
      for (int nf = 0; nf < 4; ++nf) {
        float p0 = __builtin_amdgcn_exp2f(sacc[mf][nf][0] - m_run[mf]);
        float p1 = __builtin_amdgcn_exp2f(sacc[mf][nf][1] - m_run[mf]);
        float p2 = __builtin_amdgcn_exp2f(sacc[mf][nf][2] - m_run[mf]);
        float p3 = __builtin_amdgcn_exp2f(sacc[mf][nf][3] - m_run[mf]);
        rs[mf] += (p0 + p1) + (p2 + p3);
        *(u32x2*)(Prow + (((nf * 16 + g4 * 4) * 2) ^ sw)) =
            (u32x2){pack_bf16_trunc(p0, p1), pack_bf16_trunc(p2, p3)};
      }
      float s = rs[mf];
      s += __shfl_xor(s, 16);
      s += __shfl_xor(s, 32);
      l_run[mf] += s;
    }

    // O += P V   (A = P rows q, B = V^T rows d; both K-contiguous in LDS)
#pragma unroll
    for (int ks = 0; ks < 2; ++ks) {
      bf16x8 vf[4];
#pragma unroll
      for (int df = 0; df < 4; ++df)
        vf[df] = read_frag(lV[cur], df * 16 + r15, ks * 32 + g4 * 8);
      bf16x8 pf[2];
#pragma unroll
      for (int mf = 0; mf < 2; ++mf)
        pf[mf] = read_frag(Pw, mf * 16 + r15, ks * 32 + g4 * 8);
      __builtin_amdgcn_s_setprio(1);
#pragma unroll
      for (int mf = 0; mf < 2; ++mf)
#pragma unroll
        for (int df = 0; df < 4; ++df)
          o_acc[mf][df] = __builtin_amdgcn_mfma_f32_16x16x32_bf16(pf[mf], vf[df], o_acc[mf][df], 0, 0, 0);
      __builtin_amdgcn_s_setprio(0);
    }
    cur ^= 1;
  }

  // epilogue: l_run lives at lane&15 = q; o_acc rows are q = g4*4+r
#pragma unroll
  for (int mf = 0; mf < 2; ++mf) {
    float rl = 1.f / l_run[mf];
    float rv[4];
#pragma unroll
    for (int r = 0; r < 4; ++r)
      rv[r] = __shfl(rl, (g4 * 4 + r) | (lane & 48));
#pragma unroll
    for (int r = 0; r < 4; ++r) {
      int row = myrow0 + mf * 16 + g4 * 4 + r;
#pragma unroll
      for (int df = 0; df < 4; ++df)
        ctx[((size_t)(b * 2048 + row)) * 1024 + h * 64 + df * 16 + r15] =
            f2bf(o_acc[mf][df][r] * rv[r]);
    }
  }
}

// ---------------------------------------------------------------- GEMM2: out
// out[8192][1024] fp32 = ctx[8192][1024] @ Wo (Bt = Wo^T [1024][1024]) + bo
// m97-structure single-buffer 2-barrier K-loop at 3 blocks/CU (R16-proven).
// Direct epilogue (R13: stores already coalesced; LDS roundtrip hurt).
__global__ __launch_bounds__(256, 3) void gemm_out(
    const unsigned short* __restrict__ A, const unsigned short* __restrict__ Bt,
    const float* __restrict__ bo, float* __restrict__ out) {
  __shared__ __align__(16) unsigned short lA[128 * 64];
  __shared__ __align__(16) unsigned short lB[128 * 64];
  int tid = threadIdx.x, lane = tid & 63, wave = tid >> 6;
  int wr = wave >> 1, wc = wave & 1;
  int bm = blockIdx.x, bn = blockIdx.y;
  const unsigned short* Ab = A + (size_t)bm * 128 * 1024;
  const unsigned short* Bb = Bt + (size_t)bn * 128 * 1024;
  int r15 = lane & 15, khi = (lane >> 4) * 8;

  f32x4 acc[4][4];
#pragma unroll
  for (int i = 0; i < 4; ++i)
#pragma unroll
    for (int j = 0; j < 4; ++j) acc[i][j] = (f32x4){0.f, 0.f, 0.f, 0.f};

#pragma unroll 1
  for (int t = 0; t < 16; ++t) {
    stage_tile<128>(Ab + t * 64, 1024, lA, tid);
    stage_tile<128>(Bb + t * 64, 1024, lB, tid);
    __syncthreads();
#pragma unroll
    for (int ks = 0; ks < 2; ++ks) {
      bf16x8 af[4], bfr[4];
#pragma unroll
      for (int i = 0; i < 4; ++i)
        af[i] = read_frag(lA, wr * 64 + i * 16 + r15, ks * 32 + khi);
#pragma unroll
      for (int j = 0; j < 4; ++j)
        bfr[j] = read_frag(lB, wc * 64 + j * 16 + r15, ks * 32 + khi);
      __builtin_amdgcn_s_setprio(1);
#pragma unroll
      for (int i = 0; i < 4; ++i)
#pragma unroll
        for (int j = 0; j < 4; ++j)
          acc[i][j] = __builtin_amdgcn_mfma_f32_16x16x32_bf16(af[i], bfr[j], acc[i][j], 0, 0, 0);
      __builtin_amdgcn_s_setprio(0);
    }
    __syncthreads();
  }

  int nbase = bn * 128 + wc * 64;
  int mbase = bm * 128 + wr * 64;
#pragma unroll
  for (int j = 0; j < 4; ++j) {
    int n = nbase + j * 16 + r15;
    float bias = bo[n];
#pragma unroll
    for (int i = 0; i < 4; ++i)
#pragma unroll
      for (int r = 0; r < 4; ++r) {
        int m = mbase + i * 16 + (lane >> 4) * 4 + r;
        out[(size_t)m * 1024 + n] = acc[i][j][r] + bias;
      }
  }
}

// ---------------------------------------------------------------- launch
extern "C" void kernel_launch(void* const* d_in, const int* in_sizes, int n_in,
                              void* d_out, int out_size, void* d_ws, size_t ws_size,
                              hipStream_t stream) {
  const float* x = (const float*)d_in[0];
  const float* Wq = (const float*)d_in[1];
  const float* Wk = (const float*)d_in[2];
  const float* Wv = (const float*)d_in[3];
  const float* Wo = (const float*)d_in[4];
  const float* bo = (const float*)d_in[5];
  float* out = (float*)d_out;

  char* ws = (char*)d_ws;
  unsigned short* xb    = (unsigned short*)(ws);                    // 16 MiB
  unsigned short* wqkvt = (unsigned short*)(ws + (16u << 20));      //  6 MiB
  unsigned short* wot   = (unsigned short*)(ws + (22u << 20));      //  2 MiB
  unsigned short* qws   = (unsigned short*)(ws + (24u << 20));      // 16 MiB
  unsigned short* kws   = (unsigned short*)(ws + (40u << 20));      // 16 MiB
  unsigned short* vtws  = (unsigned short*)(ws + (56u << 20));      // 16 MiB
  unsigned short* ctxws = (unsigned short*)(ws + (72u << 20));      // 16 MiB  (total 88 MiB)

  prep_inputs<<<dim3(5120), dim3(256), 0, stream>>>(x, Wq, Wk, Wv, Wo, xb, wqkvt, wot);

  gemm_qkv<<<dim3(64, 24), dim3(256), 0, stream>>>(xb, wqkvt, qws, kws, vtws);
  attn<<<dim3(8, 128), dim3(256), 0, stream>>>(qws, kws, vtws, ctxws);
  gemm_out<<<dim3(64, 8), dim3(256), 0, stream>>>(ctxws, wot, bo, out);
}